// Round 7
// baseline (213.177 us; speedup 1.0000x reference)
//
#include <hip/hip_runtime.h>

#define EPSV 1e-8f
#define PW   34          // 32 + 2 halo (zero pad)
#define NPIX 1024
#define NA   5
#define NOUT 17
#define NZC  150
#define MAXS 8           // max supported step_size (harness uses 4)

// 512 threads = 8 waves; each thread owns 2 vertically-adjacent pixels
// (rows 2*yr, 2*yr+1). Their 3x3 stencils overlap: 10 LDS taps + 2 reg
// centers serve both pixels -> ~6 LDS instrs/thread/iter (5x ds_read2 +
// 1x ds_write2). Halves VI LDS-pipe pressure vs 1px/thread.
__global__ __launch_bounds__(512, 2) void vin_fused(
    const float* __restrict__ map_in, const float* __restrict__ b0,
    const int*   __restrict__ act_in, const float* __restrict__ obs_in,
    const int*   __restrict__ step_p, const int*   __restrict__ vik_p,
    const float* __restrict__ Tb_w,  const float* __restrict__ Tb_b,
    const float* __restrict__ Tv_w,  const float* __restrict__ Tv_b,
    const float* __restrict__ Z1_w,  const float* __restrict__ Z1_b,
    const float* __restrict__ Z2_w,  const float* __restrict__ Z2_b,
    const float* __restrict__ O1_w,  const float* __restrict__ O1_b,
    const float* __restrict__ O3_w,  const float* __restrict__ O3_b,
    const float* __restrict__ R1_w,  const float* __restrict__ R1_b,
    const float* __restrict__ R2_w,  const float* __restrict__ R2_b,
    const float* __restrict__ FL_w,  const float* __restrict__ FL_b,
    float* __restrict__ out, int B)
{
    __shared__ float map0[PW*PW], map1[PW*PW];
    __shared__ float v_a[PW*PW], v_b[PW*PW], b_lds[PW*PW];
    __shared__ float zc_w[NOUT*9], zc_b[NOUT];
    __shared__ float h_all[MAXS][NOUT], u_all[MAXS][NOUT], w_all[MAXS][NOUT];
    __shared__ float zo_lds[MAXS * NPIX];
    __shared__ float partials[8][6], sums[6];

    const int tid  = threadIdx.x;          // 0..511
    const int blk  = blockIdx.x;
    const int x    = tid & 31;
    const int yr   = tid >> 5;             // 0..15 (row-pair)
    const int y0   = yr * 2;
    const int p0   = y0*32 + x, p1 = p0 + 32;      // pixel ids
    const int bi   = y0*PW + x;            // padded top-left of px0's 3x3
    const int ci0  = bi + PW + 1;          // padded center of px0
    const int ci1  = bi + 2*PW + 1;        // padded center of px1
    const int lane = tid & 63, wvid = tid >> 6;    // 8 waves

    const int S = step_p[0];
    const int K = vik_p[0];

    // ---- init: zero-padded LDS tiles ----
    for (int i = tid; i < PW*PW; i += 512) {
        map0[i] = 0.f; map1[i] = 0.f; v_a[i] = 0.f; v_b[i] = 0.f; b_lds[i] = 0.f;
    }
    __syncthreads();
    map0[ci0] = map_in[blk*2*NPIX + p0];
    map0[ci1] = map_in[blk*2*NPIX + p1];
    map1[ci0] = map_in[blk*2*NPIX + NPIX + p0];
    map1[ci1] = map_in[blk*2*NPIX + NPIX + p1];
    float bc0 = b0[blk*NPIX + p0];
    float bc1 = b0[blk*NPIX + p1];
    b_lds[ci0] = bc0; b_lds[ci1] = bc1;

    // ---- collapse Z2(1x1) o Z1(3x3) into one 17-ch 3x3 conv ----
    if (tid < NOUT*9) {
        const int o = tid / 9, k = tid % 9;
        float s = 0.f;
        for (int c = 0; c < NZC; ++c) s += Z2_w[o*NZC + c] * Z1_w[c*9 + k];
        zc_w[tid] = s;
    } else if (tid < NOUT*9 + NOUT) {
        const int o = tid - NOUT*9;
        float s = Z2_b[o];
        for (int c = 0; c < NZC; ++c) s += Z2_w[o*NZC + c] * Z1_b[c];
        zc_b[o] = s;
    }

    // ---- observation MLP for ALL timesteps upfront (threads 256..256+S*17) ----
    const int mt = tid - 256;
    const int mT = mt / NOUT, mO = mt % NOUT;
    if (mt >= 0 && mt < S*NOUT) {
        const float* ob = obs_in + (blk*S + mT)*4;
        float hh = O1_b[mO];
        #pragma unroll
        for (int k = 0; k < 4; ++k) hh += ob[k] * O1_w[mO*4 + k];
        h_all[mT][mO] = tanhf(hh);
    }
    __syncthreads();
    if (mt >= 0 && mt < S*NOUT) {
        float u = O3_b[mO];
        #pragma unroll
        for (int j = 0; j < NOUT; ++j) u += h_all[mT][j] * O3_w[mO*NOUT + j];
        u_all[mT][mO] = u;
    }
    __syncthreads();
    if (mt >= 0 && mt < S*NOUT) {
        float mx = u_all[mT][0];
        #pragma unroll
        for (int j = 1; j < NOUT; ++j) mx = fmaxf(mx, u_all[mT][j]);
        float sm = 0.f;
        #pragma unroll
        for (int j = 0; j < NOUT; ++j) sm += expf(u_all[mT][j] - mx);
        w_all[mT][mO] = expf(u_all[mT][mO] - mx) / sm;
    }
    __syncthreads();

    // ---- map stencil: union of both pixels' 3x3 = 4 rows x 3 cols ----
    float m0[12], m1[12];
    #pragma unroll
    for (int kr = 0; kr < 4; ++kr)
        #pragma unroll
        for (int kc = 0; kc < 3; ++kc) {
            const int off = bi + kr*PW + kc;
            m0[kr*3+kc] = map0[off]; m1[kr*3+kc] = map1[off];
        }
    // px0 uses m[0..8], px1 uses m[3..11]

    // ---- R = conv1x1(relu(conv3x3(map))) for both pixels ----
    float r0a[NA], r1a[NA];
    #pragma unroll
    for (int a = 0; a < NA; ++a) { r0a[a] = R2_b[a]; r1a[a] = R2_b[a]; }
    for (int c = 0; c < NZC; ++c) {
        const float* w1 = R1_w + c*18;
        float s0 = R1_b[c], s1 = R1_b[c];
        #pragma unroll
        for (int k = 0; k < 9; ++k) { s0 += m0[k]   * w1[k];   s1 += m0[3+k] * w1[k]; }
        #pragma unroll
        for (int k = 0; k < 9; ++k) { s0 += m1[k]   * w1[9+k]; s1 += m1[3+k] * w1[9+k]; }
        s0 = fmaxf(s0, 0.f); s1 = fmaxf(s1, 0.f);
        #pragma unroll
        for (int a = 0; a < NA; ++a) {
            r0a[a] += R2_w[a*NZC + c] * s0;
            r1a[a] += R2_w[a*NZC + c] * s1;
        }
    }

    // ---- Z per pixel (sequential to keep z[17] short-lived) ----
    {
        float z[NOUT]; float zs;
        // px0
        zs = 0.f;
        #pragma unroll
        for (int o = 0; o < NOUT; ++o) {
            float s = zc_b[o];
            #pragma unroll
            for (int k = 0; k < 9; ++k) s += m0[k] * zc_w[o*9 + k];
            const float zz = 1.f / (1.f + expf(-s));
            z[o] = zz; zs += zz;
        }
        {
            const float zn = 1.f / (zs + EPSV);
            for (int t = 0; t < S; ++t) {
                float zo = 0.f;
                #pragma unroll
                for (int o = 0; o < NOUT; ++o) zo += z[o] * w_all[t][o];
                zo_lds[t*NPIX + p0] = zo * zn;
            }
        }
        // px1
        zs = 0.f;
        #pragma unroll
        for (int o = 0; o < NOUT; ++o) {
            float s = zc_b[o];
            #pragma unroll
            for (int k = 0; k < 9; ++k) s += m0[3+k] * zc_w[o*9 + k];
            const float zz = 1.f / (1.f + expf(-s));
            z[o] = zz; zs += zz;
        }
        {
            const float zn = 1.f / (zs + EPSV);
            for (int t = 0; t < S; ++t) {
                float zo = 0.f;
                #pragma unroll
                for (int o = 0; o < NOUT; ++o) zo += z[o] * w_all[t][o];
                zo_lds[t*NPIX + p1] = zo * zn;
            }
        }
    }

    // ---- value iteration: ping-pong, 1 barrier/iter, 2 px/thread.
    //      10 shared taps + 2 reg centers serve both 3x3 stencils. ----
    float q0[NA], q1[NA];
    #pragma unroll
    for (int a = 0; a < NA; ++a) {
        q0[a] = 0.f; q1[a] = 0.f;
        r0a[a] += Tv_b[a]; r1a[a] += Tv_b[a];   // hoist bias
    }
    float vc0 = 0.f, vc1 = 0.f;

#define VISTEP(SRC, DST)                                                        \
    {                                                                           \
        const float A0 = SRC[bi],        A1 = SRC[bi+1],        A2 = SRC[bi+2]; \
        const float B0 = SRC[bi+PW],     B2 = SRC[bi+PW+2];                     \
        const float C0 = SRC[bi+2*PW],   C2 = SRC[bi+2*PW+2];                   \
        const float D0 = SRC[bi+3*PW],   D1 = SRC[bi+3*PW+1],   D2 = SRC[bi+3*PW+2]; \
        float vm0 = -3.4e38f, vm1 = -3.4e38f;                                   \
        _Pragma("unroll")                                                       \
        for (int a = 0; a < NA; ++a) {                                          \
            const float* w = Tv_w + a*9;                                        \
            float s0 = r0a[a];                                                  \
            s0 += A0*w[0]; s0 += A1*w[1]; s0 += A2*w[2];                        \
            s0 += B0*w[3]; s0 += vc0*w[4]; s0 += B2*w[5];                       \
            s0 += C0*w[6]; s0 += vc1*w[7]; s0 += C2*w[8];                       \
            float s1 = r1a[a];                                                  \
            s1 += B0*w[0]; s1 += vc0*w[1]; s1 += B2*w[2];                       \
            s1 += C0*w[3]; s1 += vc1*w[4]; s1 += C2*w[5];                       \
            s1 += D0*w[6]; s1 += D1*w[7]; s1 += D2*w[8];                        \
            q0[a] = s0; q1[a] = s1;                                             \
            vm0 = fmaxf(vm0, s0); vm1 = fmaxf(vm1, s1);                         \
        }                                                                       \
        vc0 = vm0; vc1 = vm1;                                                   \
        DST[ci0] = vm0; DST[ci1] = vm1;                                         \
        __syncthreads();                                                        \
    }

    {
        int it = 0;
        for (; it + 1 < K; it += 2) { VISTEP(v_a, v_b); VISTEP(v_b, v_a); }
        if (it < K) { VISTEP(v_a, v_b); }
    }
#undef VISTEP

    // ---- belief-propagation timestep loop ----
    for (int t = 0; t < S; ++t) {
        const int a_t = act_in[blk*S + t];     // block-uniform
        const float* tw = Tb_w + a_t*9;
        const float tb = Tb_b[a_t];
        float bp0 = tb, bp1 = tb;
        {
            const float A0 = b_lds[bi],      A1 = b_lds[bi+1],      A2 = b_lds[bi+2];
            const float B0 = b_lds[bi+PW],   B2 = b_lds[bi+PW+2];
            const float C0 = b_lds[bi+2*PW], C2 = b_lds[bi+2*PW+2];
            const float D0 = b_lds[bi+3*PW], D1 = b_lds[bi+3*PW+1], D2 = b_lds[bi+3*PW+2];
            bp0 += A0*tw[0]; bp0 += A1*tw[1]; bp0 += A2*tw[2];
            bp0 += B0*tw[3]; bp0 += bc0*tw[4]; bp0 += B2*tw[5];
            bp0 += C0*tw[6]; bp0 += bc1*tw[7]; bp0 += C2*tw[8];
            bp1 += B0*tw[0]; bp1 += bc0*tw[1]; bp1 += B2*tw[2];
            bp1 += C0*tw[3]; bp1 += bc1*tw[4]; bp1 += C2*tw[5];
            bp1 += D0*tw[6]; bp1 += D1*tw[7]; bp1 += D2*tw[8];
        }

        const float bn0 = bp0 * zo_lds[t*NPIX + p0];
        const float bn1 = bp1 * zo_lds[t*NPIX + p1];

        // fused 6-way reduction over both pixels
        float v6[6];
        v6[5] = bn0 + bn1;
        #pragma unroll
        for (int a = 0; a < NA; ++a) v6[a] = q0[a]*bn0 + q1[a]*bn1;
        #pragma unroll
        for (int k = 0; k < 6; ++k) {
            float vv = v6[k];
            for (int off = 32; off > 0; off >>= 1) vv += __shfl_down(vv, off);
            v6[k] = vv;
        }
        if (lane == 0) {
            #pragma unroll
            for (int k = 0; k < 6; ++k) partials[wvid][k] = v6[k];
        }
        __syncthreads();
        if (tid < 6) {
            float s = 0.f;
            for (int w2 = 0; w2 < 8; ++w2) s += partials[w2][tid];
            sums[tid] = s;
        }
        __syncthreads();

        const float inv = 1.f / (sums[5] + EPSV);
        if (tid < NA) {
            float oj = FL_b[tid];
            #pragma unroll
            for (int a = 0; a < NA; ++a) oj += (sums[a] * inv) * FL_w[tid*NA + a];
            out[(t*B + blk)*NA + tid] = oj;
        }
        bc0 = bn0 * inv; bc1 = bn1 * inv;
        b_lds[ci0] = bc0; b_lds[ci1] = bc1;
        __syncthreads();
    }

    // ---- final belief output (own values in regs) ----
    out[S*B*NA + blk*NPIX + p0] = bc0;
    out[S*B*NA + blk*NPIX + p1] = bc1;
}

extern "C" void kernel_launch(void* const* d_in, const int* in_sizes, int n_in,
                              void* d_out, int out_size, void* d_ws, size_t ws_size,
                              hipStream_t stream)
{
    const float* map_in = (const float*)d_in[0];
    const float* b0     = (const float*)d_in[1];
    const int*   act_in = (const int*)  d_in[2];
    const float* obs_in = (const float*)d_in[3];
    // d_in[4] = is_start (unused: reference uses b0 either way)
    const int*   step_p = (const int*)  d_in[5];
    const int*   vik_p  = (const int*)  d_in[6];
    const float* Tb_w = (const float*)d_in[7];
    const float* Tb_b = (const float*)d_in[8];
    const float* Tv_w = (const float*)d_in[9];
    const float* Tv_b = (const float*)d_in[10];
    const float* Z1_w = (const float*)d_in[11];
    const float* Z1_b = (const float*)d_in[12];
    const float* Z2_w = (const float*)d_in[13];
    const float* Z2_b = (const float*)d_in[14];
    const float* O1_w = (const float*)d_in[15];
    const float* O1_b = (const float*)d_in[16];
    const float* O3_w = (const float*)d_in[17];
    const float* O3_b = (const float*)d_in[18];
    const float* R1_w = (const float*)d_in[19];
    const float* R1_b = (const float*)d_in[20];
    const float* R2_w = (const float*)d_in[21];
    const float* R2_b = (const float*)d_in[22];
    const float* FL_w = (const float*)d_in[23];
    const float* FL_b = (const float*)d_in[24];

    const int B = in_sizes[1] / NPIX;   // b0 is (B,32,32)

    hipLaunchKernelGGL(vin_fused, dim3(B), dim3(512), 0, stream,
        map_in, b0, act_in, obs_in, step_p, vik_p,
        Tb_w, Tb_b, Tv_w, Tv_b, Z1_w, Z1_b, Z2_w, Z2_b,
        O1_w, O1_b, O3_w, O3_b, R1_w, R1_b, R2_w, R2_b,
        FL_w, FL_b, (float*)d_out, B);
}

// Round 9
// 197.897 us; speedup vs baseline: 1.0772x; 1.0772x over previous
//
#include <hip/hip_runtime.h>

#define EPSV 1e-8f
#define PW   34          // 32 + 2 halo (zero pad)
#define NPIX 1024
#define NA   5
#define NOUT 17
#define NZC  150
#define MAXS 8           // max supported step_size (harness uses 4)

// block=1024 (1 image/block), 1 block/CU. R5 structure; ONLY change vs R5:
// VI uses ping-pong v buffers -> 1 barrier/iter instead of 2.
__global__ __launch_bounds__(1024, 4) void vin_fused(
    const float* __restrict__ map_in, const float* __restrict__ b0,
    const int*   __restrict__ act_in, const float* __restrict__ obs_in,
    const int*   __restrict__ step_p, const int*   __restrict__ vik_p,
    const float* __restrict__ Tb_w,  const float* __restrict__ Tb_b,
    const float* __restrict__ Tv_w,  const float* __restrict__ Tv_b,
    const float* __restrict__ Z1_w,  const float* __restrict__ Z1_b,
    const float* __restrict__ Z2_w,  const float* __restrict__ Z2_b,
    const float* __restrict__ O1_w,  const float* __restrict__ O1_b,
    const float* __restrict__ O3_w,  const float* __restrict__ O3_b,
    const float* __restrict__ R1_w,  const float* __restrict__ R1_b,
    const float* __restrict__ R2_w,  const float* __restrict__ R2_b,
    const float* __restrict__ FL_w,  const float* __restrict__ FL_b,
    float* __restrict__ out, int B)
{
    __shared__ float map0[PW*PW], map1[PW*PW];
    __shared__ float v_a[PW*PW], v_b[PW*PW], b_lds[PW*PW];
    __shared__ float zc_w[NOUT*9], zc_b[NOUT];
    __shared__ float h_all[MAXS][NOUT], u_all[MAXS][NOUT], w_all[MAXS][NOUT];
    __shared__ float zo_lds[MAXS * NPIX];
    __shared__ float partials[16][6], sums[6];

    const int tid  = threadIdx.x;
    const int blk  = blockIdx.x;
    const int y    = tid >> 5, x = tid & 31;
    const int pidx = (y + 1) * PW + (x + 1);
    const int bi   = y * PW + x;           // top-left of 3x3 neighborhood
    const int lane = tid & 63, wvid = tid >> 6;

    const int S = step_p[0];
    const int K = vik_p[0];

    // ---- init: zero-padded LDS tiles ----
    for (int i = tid; i < PW*PW; i += NPIX) {
        map0[i] = 0.f; map1[i] = 0.f; v_a[i] = 0.f; v_b[i] = 0.f; b_lds[i] = 0.f;
    }
    __syncthreads();
    map0[pidx]  = map_in[blk*2*NPIX + tid];
    map1[pidx]  = map_in[blk*2*NPIX + NPIX + tid];
    b_lds[pidx] = b0[blk*NPIX + tid];

    // ---- collapse Z2(1x1) o Z1(3x3) into one 17-ch 3x3 conv ----
    if (tid < NOUT*9) {
        const int o = tid / 9, k = tid % 9;
        float s = 0.f;
        for (int c = 0; c < NZC; ++c) s += Z2_w[o*NZC + c] * Z1_w[c*9 + k];
        zc_w[tid] = s;
    } else if (tid < NOUT*9 + NOUT) {
        const int o = tid - NOUT*9;
        float s = Z2_b[o];
        for (int c = 0; c < NZC; ++c) s += Z2_w[o*NZC + c] * Z1_b[c];
        zc_b[o] = s;
    }

    // ---- observation MLP for ALL timesteps upfront (threads 256..256+S*17) ----
    const int mt = tid - 256;
    const int mT = mt / NOUT, mO = mt % NOUT;
    if (mt >= 0 && mt < S*NOUT) {
        const float* ob = obs_in + (blk*S + mT)*4;
        float hh = O1_b[mO];
        #pragma unroll
        for (int k = 0; k < 4; ++k) hh += ob[k] * O1_w[mO*4 + k];
        h_all[mT][mO] = tanhf(hh);
    }
    __syncthreads();
    if (mt >= 0 && mt < S*NOUT) {
        float u = O3_b[mO];
        #pragma unroll
        for (int j = 0; j < NOUT; ++j) u += h_all[mT][j] * O3_w[mO*NOUT + j];
        u_all[mT][mO] = u;
    }
    __syncthreads();
    if (mt >= 0 && mt < S*NOUT) {
        float mx = u_all[mT][0];
        #pragma unroll
        for (int j = 1; j < NOUT; ++j) mx = fmaxf(mx, u_all[mT][j]);
        float sm = 0.f;
        #pragma unroll
        for (int j = 0; j < NOUT; ++j) sm += expf(u_all[mT][j] - mx);
        w_all[mT][mO] = expf(u_all[mT][mO] - mx) / sm;
    }
    __syncthreads();

    // ---- stencil neighborhood into registers ----
    float m0[9], m1[9];
    #pragma unroll
    for (int k = 0; k < 9; ++k) {
        const int off = bi + (k/3)*PW + (k%3);
        m0[k] = map0[off]; m1[k] = map1[off];
    }

    // ---- R = conv1x1(relu(conv3x3(map))); weights wave-uniform -> s_load ----
    float r[NA];
    #pragma unroll
    for (int a = 0; a < NA; ++a) r[a] = R2_b[a];
    for (int c = 0; c < NZC; ++c) {
        float s = R1_b[c];
        const float* w1 = R1_w + c*18;
        #pragma unroll
        for (int k = 0; k < 9; ++k) s += m0[k] * w1[k];
        #pragma unroll
        for (int k = 0; k < 9; ++k) s += m1[k] * w1[9 + k];
        s = fmaxf(s, 0.f);
        #pragma unroll
        for (int a = 0; a < NA; ++a) r[a] += R2_w[a*NZC + c] * s;
    }

    // ---- Z: sigmoid(collapsed conv), normalized, collapsed against w_t ----
    {
        float z[NOUT];
        float zs = 0.f;
        #pragma unroll
        for (int o = 0; o < NOUT; ++o) {
            float s = zc_b[o];
            #pragma unroll
            for (int k = 0; k < 9; ++k) s += m0[k] * zc_w[o*9 + k];
            const float zz = 1.f / (1.f + expf(-s));
            z[o] = zz; zs += zz;
        }
        const float zn = 1.f / (zs + EPSV);
        for (int t = 0; t < S; ++t) {
            float zo = 0.f;
            #pragma unroll
            for (int o = 0; o < NOUT; ++o) zo += z[o] * w_all[t][o];
            zo_lds[t*NPIX + tid] = zo * zn;
        }
    }

    // ---- value iteration: ping-pong, ONE barrier/iter. Reads (9 taps) at
    //      top issue right after the barrier; barrier-arrival implies each
    //      wave's reads landed (lgkmcnt(0) precedes s_barrier), so writing
    //      the other buffer after one barrier is WAR-safe. ----
    float q[NA];
    #pragma unroll
    for (int a = 0; a < NA; ++a) q[a] = 0.f;

#define VISTEP(SRC, DST)                                                      \
    {                                                                         \
        float n[9];                                                           \
        _Pragma("unroll")                                                     \
        for (int k = 0; k < 9; ++k) n[k] = SRC[bi + (k/3)*PW + (k%3)];        \
        float vmax = -3.4e38f;                                                \
        _Pragma("unroll")                                                     \
        for (int a = 0; a < NA; ++a) {                                        \
            float s = Tv_b[a] + r[a];                                         \
            _Pragma("unroll")                                                 \
            for (int k = 0; k < 9; ++k) s += n[k] * Tv_w[a*9 + k];            \
            q[a] = s;                                                         \
            vmax = fmaxf(vmax, s);                                            \
        }                                                                     \
        DST[pidx] = vmax;                                                     \
        __syncthreads();                                                      \
    }

    {
        int it = 0;
        for (; it + 1 < K; it += 2) { VISTEP(v_a, v_b); VISTEP(v_b, v_a); }
        if (it < K) { VISTEP(v_a, v_b); }
    }
#undef VISTEP

    // ---- belief-propagation timestep loop (identical to R5) ----
    for (int t = 0; t < S; ++t) {
        const int a_t = act_in[blk*S + t];     // block-uniform
        float bp = Tb_b[a_t];
        #pragma unroll
        for (int k = 0; k < 9; ++k)
            bp += b_lds[bi + (k/3)*PW + (k%3)] * Tb_w[a_t*9 + k];

        const float bn = bp * zo_lds[t*NPIX + tid];

        // fused 6-way reduction: sums[0..4] = sum q[a]*bn, sums[5] = sum bn
        float v6[6];
        v6[5] = bn;
        #pragma unroll
        for (int a = 0; a < NA; ++a) v6[a] = q[a] * bn;
        #pragma unroll
        for (int k = 0; k < 6; ++k) {
            float vv = v6[k];
            for (int off = 32; off > 0; off >>= 1) vv += __shfl_down(vv, off);
            v6[k] = vv;
        }
        if (lane == 0) {
            #pragma unroll
            for (int k = 0; k < 6; ++k) partials[wvid][k] = v6[k];
        }
        __syncthreads();
        if (tid < 6) {
            float s = 0.f;
            for (int w2 = 0; w2 < 16; ++w2) s += partials[w2][tid];
            sums[tid] = s;
        }
        __syncthreads();

        const float inv = 1.f / (sums[5] + EPSV);
        if (tid < NA) {
            float oj = FL_b[tid];
            #pragma unroll
            for (int a = 0; a < NA; ++a) oj += (sums[a] * inv) * FL_w[tid*NA + a];
            out[(t*B + blk)*NA + tid] = oj;
        }
        b_lds[pidx] = bn * inv;   // normalized belief for next step
        __syncthreads();
    }

    // ---- final belief output ----
    out[S*B*NA + blk*NPIX + tid] = b_lds[pidx];
}

extern "C" void kernel_launch(void* const* d_in, const int* in_sizes, int n_in,
                              void* d_out, int out_size, void* d_ws, size_t ws_size,
                              hipStream_t stream)
{
    const float* map_in = (const float*)d_in[0];
    const float* b0     = (const float*)d_in[1];
    const int*   act_in = (const int*)  d_in[2];
    const float* obs_in = (const float*)d_in[3];
    // d_in[4] = is_start (unused: reference uses b0 either way)
    const int*   step_p = (const int*)  d_in[5];
    const int*   vik_p  = (const int*)  d_in[6];
    const float* Tb_w = (const float*)d_in[7];
    const float* Tb_b = (const float*)d_in[8];
    const float* Tv_w = (const float*)d_in[9];
    const float* Tv_b = (const float*)d_in[10];
    const float* Z1_w = (const float*)d_in[11];
    const float* Z1_b = (const float*)d_in[12];
    const float* Z2_w = (const float*)d_in[13];
    const float* Z2_b = (const float*)d_in[14];
    const float* O1_w = (const float*)d_in[15];
    const float* O1_b = (const float*)d_in[16];
    const float* O3_w = (const float*)d_in[17];
    const float* O3_b = (const float*)d_in[18];
    const float* R1_w = (const float*)d_in[19];
    const float* R1_b = (const float*)d_in[20];
    const float* R2_w = (const float*)d_in[21];
    const float* R2_b = (const float*)d_in[22];
    const float* FL_w = (const float*)d_in[23];
    const float* FL_b = (const float*)d_in[24];

    const int B = in_sizes[1] / NPIX;   // b0 is (B,32,32)

    hipLaunchKernelGGL(vin_fused, dim3(B), dim3(1024), 0, stream,
        map_in, b0, act_in, obs_in, step_p, vik_p,
        Tb_w, Tb_b, Tv_w, Tv_b, Z1_w, Z1_b, Z2_w, Z2_b,
        O1_w, O1_b, O3_w, O3_b, R1_w, R1_b, R2_w, R2_b,
        FL_w, FL_b, (float*)d_out, B);
}

// Round 12
// 187.644 us; speedup vs baseline: 1.1361x; 1.0546x over previous
//
#include <hip/hip_runtime.h>

#define EPSV 1e-8f
#define PW   34          // 32 + 2 halo (zero pad)
#define NPIX 1024
#define NA   5
#define NOUT 17
#define NZC  150
#define MAXS 8           // max supported step_size (harness uses 4)

// block=1024 (1 image/block), 1 block/CU. R5-measured structure (2-barrier
// single-buffer VI — banked best, R6/R9 refuted ping-pong). ONLY change:
// R-conv processes 2 channels/iter with independent accumulators (ILP +
// SMEM overlap).
__global__ __launch_bounds__(1024, 4) void vin_fused(
    const float* __restrict__ map_in, const float* __restrict__ b0,
    const int*   __restrict__ act_in, const float* __restrict__ obs_in,
    const int*   __restrict__ step_p, const int*   __restrict__ vik_p,
    const float* __restrict__ Tb_w,  const float* __restrict__ Tb_b,
    const float* __restrict__ Tv_w,  const float* __restrict__ Tv_b,
    const float* __restrict__ Z1_w,  const float* __restrict__ Z1_b,
    const float* __restrict__ Z2_w,  const float* __restrict__ Z2_b,
    const float* __restrict__ O1_w,  const float* __restrict__ O1_b,
    const float* __restrict__ O3_w,  const float* __restrict__ O3_b,
    const float* __restrict__ R1_w,  const float* __restrict__ R1_b,
    const float* __restrict__ R2_w,  const float* __restrict__ R2_b,
    const float* __restrict__ FL_w,  const float* __restrict__ FL_b,
    float* __restrict__ out, int B)
{
    __shared__ float map0[PW*PW], map1[PW*PW], v_lds[PW*PW], b_lds[PW*PW];
    __shared__ float zc_w[NOUT*9], zc_b[NOUT];
    __shared__ float h_all[MAXS][NOUT], u_all[MAXS][NOUT], w_all[MAXS][NOUT];
    __shared__ float zo_lds[MAXS * NPIX];
    __shared__ float partials[16][6], sums[6];

    const int tid  = threadIdx.x;
    const int blk  = blockIdx.x;
    const int y    = tid >> 5, x = tid & 31;
    const int pidx = (y + 1) * PW + (x + 1);
    const int lane = tid & 63, wvid = tid >> 6;

    const int S = step_p[0];
    const int K = vik_p[0];

    // ---- init: zero-padded LDS tiles ----
    for (int i = tid; i < PW*PW; i += NPIX) {
        map0[i] = 0.f; map1[i] = 0.f; v_lds[i] = 0.f; b_lds[i] = 0.f;
    }
    __syncthreads();
    map0[pidx]  = map_in[blk*2*NPIX + tid];
    map1[pidx]  = map_in[blk*2*NPIX + NPIX + tid];
    b_lds[pidx] = b0[blk*NPIX + tid];

    // ---- collapse Z2(1x1) o Z1(3x3) into one 17-ch 3x3 conv ----
    if (tid < NOUT*9) {
        const int o = tid / 9, k = tid % 9;
        float s = 0.f;
        for (int c = 0; c < NZC; ++c) s += Z2_w[o*NZC + c] * Z1_w[c*9 + k];
        zc_w[tid] = s;
    } else if (tid < NOUT*9 + NOUT) {
        const int o = tid - NOUT*9;
        float s = Z2_b[o];
        for (int c = 0; c < NZC; ++c) s += Z2_w[o*NZC + c] * Z1_b[c];
        zc_b[o] = s;
    }

    // ---- observation MLP for ALL timesteps upfront (threads 256..256+S*17) ----
    const int mt = tid - 256;
    const int mT = mt / NOUT, mO = mt % NOUT;
    if (mt >= 0 && mt < S*NOUT) {
        const float* ob = obs_in + (blk*S + mT)*4;
        float hh = O1_b[mO];
        #pragma unroll
        for (int k = 0; k < 4; ++k) hh += ob[k] * O1_w[mO*4 + k];
        h_all[mT][mO] = tanhf(hh);
    }
    __syncthreads();
    if (mt >= 0 && mt < S*NOUT) {
        float u = O3_b[mO];
        #pragma unroll
        for (int j = 0; j < NOUT; ++j) u += h_all[mT][j] * O3_w[mO*NOUT + j];
        u_all[mT][mO] = u;
    }
    __syncthreads();
    if (mt >= 0 && mt < S*NOUT) {
        float mx = u_all[mT][0];
        #pragma unroll
        for (int j = 1; j < NOUT; ++j) mx = fmaxf(mx, u_all[mT][j]);
        float sm = 0.f;
        #pragma unroll
        for (int j = 0; j < NOUT; ++j) sm += expf(u_all[mT][j] - mx);
        w_all[mT][mO] = expf(u_all[mT][mO] - mx) / sm;
    }
    __syncthreads();

    // ---- stencil neighborhood into registers ----
    float m0[9], m1[9];
    #pragma unroll
    for (int k = 0; k < 9; ++k) {
        const int off = (y + k/3)*PW + x + (k%3);
        m0[k] = map0[off]; m1[k] = map1[off];
    }

    // ---- R = conv1x1(relu(conv3x3(map))): 2 channels/iter, independent
    //      accumulator sets rA/rB -> 2 overlapping SMEM+FMA chains ----
    float rA[NA], rB[NA];
    #pragma unroll
    for (int a = 0; a < NA; ++a) { rA[a] = R2_b[a]; rB[a] = 0.f; }
    for (int c = 0; c < NZC; c += 2) {           // NZC=150 even, no tail
        const float* w1a = R1_w + c*18;
        const float* w1b = w1a + 18;
        float s0 = R1_b[c], s1 = R1_b[c+1];
        #pragma unroll
        for (int k = 0; k < 9; ++k) { s0 += m0[k] * w1a[k];   s1 += m0[k] * w1b[k]; }
        #pragma unroll
        for (int k = 0; k < 9; ++k) { s0 += m1[k] * w1a[9+k]; s1 += m1[k] * w1b[9+k]; }
        s0 = fmaxf(s0, 0.f); s1 = fmaxf(s1, 0.f);
        #pragma unroll
        for (int a = 0; a < NA; ++a) {
            rA[a] += R2_w[a*NZC + c]     * s0;
            rB[a] += R2_w[a*NZC + c + 1] * s1;
        }
    }
    float r[NA];
    #pragma unroll
    for (int a = 0; a < NA; ++a) r[a] = rA[a] + rB[a];

    // ---- Z: sigmoid(collapsed conv), normalized, collapsed against w_t ----
    {
        float z[NOUT];
        float zs = 0.f;
        #pragma unroll
        for (int o = 0; o < NOUT; ++o) {
            float s = zc_b[o];
            #pragma unroll
            for (int k = 0; k < 9; ++k) s += m0[k] * zc_w[o*9 + k];
            const float zz = 1.f / (1.f + expf(-s));
            z[o] = zz; zs += zz;
        }
        const float zn = 1.f / (zs + EPSV);
        for (int t = 0; t < S; ++t) {
            float zo = 0.f;
            #pragma unroll
            for (int o = 0; o < NOUT; ++o) zo += z[o] * w_all[t][o];
            zo_lds[t*NPIX + tid] = zo * zn;
        }
    }

    // ---- value iteration: single buffer, 2 barriers/iter (banked best) ----
    float q[NA];
    #pragma unroll
    for (int a = 0; a < NA; ++a) q[a] = 0.f;
    for (int it = 0; it < K; ++it) {
        float n[9];
        #pragma unroll
        for (int k = 0; k < 9; ++k) n[k] = v_lds[(y + k/3)*PW + x + (k%3)];
        float vmax = -3.4e38f;
        #pragma unroll
        for (int a = 0; a < NA; ++a) {
            float s = Tv_b[a] + r[a];
            #pragma unroll
            for (int k = 0; k < 9; ++k) s += n[k] * Tv_w[a*9 + k];
            q[a] = s;
            vmax = fmaxf(vmax, s);
        }
        __syncthreads();
        v_lds[pidx] = vmax;
        __syncthreads();
    }

    // ---- belief-propagation timestep loop ----
    for (int t = 0; t < S; ++t) {
        const int a_t = act_in[blk*S + t];     // block-uniform
        float bp = Tb_b[a_t];
        #pragma unroll
        for (int k = 0; k < 9; ++k)
            bp += b_lds[(y + k/3)*PW + x + (k%3)] * Tb_w[a_t*9 + k];

        const float bn = bp * zo_lds[t*NPIX + tid];

        // fused 6-way reduction: sums[0..4] = sum q[a]*bn, sums[5] = sum bn
        float v6[6];
        v6[5] = bn;
        #pragma unroll
        for (int a = 0; a < NA; ++a) v6[a] = q[a] * bn;
        #pragma unroll
        for (int k = 0; k < 6; ++k) {
            float vv = v6[k];
            for (int off = 32; off > 0; off >>= 1) vv += __shfl_down(vv, off);
            v6[k] = vv;
        }
        if (lane == 0) {
            #pragma unroll
            for (int k = 0; k < 6; ++k) partials[wvid][k] = v6[k];
        }
        __syncthreads();
        if (tid < 6) {
            float s = 0.f;
            for (int w2 = 0; w2 < 16; ++w2) s += partials[w2][tid];
            sums[tid] = s;
        }
        __syncthreads();

        const float inv = 1.f / (sums[5] + EPSV);
        if (tid < NA) {
            float oj = FL_b[tid];
            #pragma unroll
            for (int a = 0; a < NA; ++a) oj += (sums[a] * inv) * FL_w[tid*NA + a];
            out[(t*B + blk)*NA + tid] = oj;
        }
        b_lds[pidx] = bn * inv;   // normalized belief for next step
        __syncthreads();
    }

    // ---- final belief output ----
    out[S*B*NA + blk*NPIX + tid] = b_lds[pidx];
}

extern "C" void kernel_launch(void* const* d_in, const int* in_sizes, int n_in,
                              void* d_out, int out_size, void* d_ws, size_t ws_size,
                              hipStream_t stream)
{
    const float* map_in = (const float*)d_in[0];
    const float* b0     = (const float*)d_in[1];
    const int*   act_in = (const int*)  d_in[2];
    const float* obs_in = (const float*)d_in[3];
    // d_in[4] = is_start (unused: reference uses b0 either way)
    const int*   step_p = (const int*)  d_in[5];
    const int*   vik_p  = (const int*)  d_in[6];
    const float* Tb_w = (const float*)d_in[7];
    const float* Tb_b = (const float*)d_in[8];
    const float* Tv_w = (const float*)d_in[9];
    const float* Tv_b = (const float*)d_in[10];
    const float* Z1_w = (const float*)d_in[11];
    const float* Z1_b = (const float*)d_in[12];
    const float* Z2_w = (const float*)d_in[13];
    const float* Z2_b = (const float*)d_in[14];
    const float* O1_w = (const float*)d_in[15];
    const float* O1_b = (const float*)d_in[16];
    const float* O3_w = (const float*)d_in[17];
    const float* O3_b = (const float*)d_in[18];
    const float* R1_w = (const float*)d_in[19];
    const float* R1_b = (const float*)d_in[20];
    const float* R2_w = (const float*)d_in[21];
    const float* R2_b = (const float*)d_in[22];
    const float* FL_w = (const float*)d_in[23];
    const float* FL_b = (const float*)d_in[24];

    const int B = in_sizes[1] / NPIX;   // b0 is (B,32,32)

    hipLaunchKernelGGL(vin_fused, dim3(B), dim3(1024), 0, stream,
        map_in, b0, act_in, obs_in, step_p, vik_p,
        Tb_w, Tb_b, Tv_w, Tv_b, Z1_w, Z1_b, Z2_w, Z2_b,
        O1_w, O1_b, O3_w, O3_b, R1_w, R1_b, R2_w, R2_b,
        FL_w, FL_b, (float*)d_out, B);
}